// Round 2
// baseline (143.332 us; speedup 1.0000x reference)
//
#include <hip/hip_runtime.h>
#include <math.h>

#define NCOL 8192
#define NROW 4096
#define KSEL 819
#define TPB 256
#define VPT 8          // float4 per thread (32 elements/thread)
#define NW 4           // waves per block
#define HPAD 264       // 256 bins + 8 pad (spreads the 4 wave-copies across banks)

// Per-column boost factors, recomputed every launch (deterministic).
__device__ __align__(16) float g_boost[NCOL];

__global__ void boost_kernel(const float* __restrict__ duty) {
    int i = blockIdx.x * blockDim.x + threadIdx.x;
    if (i < NCOL) {
        // target_density = 819/8192 exactly; boost_strength = 1
        float diff = (0.0999755859375f - duty[i]);
        g_boost[i] = (float)exp((double)diff);   // correctly-rounded f32 exp (matches np)
    }
}

__device__ __forceinline__ unsigned f2k(float f) {
    // monotone float -> uint map (total order)
    unsigned u = __float_as_uint(f);
    return u ^ (0x80000000u | (unsigned)((int)u >> 31));
}

__global__ __launch_bounds__(TPB, 8) void kwinners_kernel(const float* __restrict__ x,
                                                          float* __restrict__ out) {
    __shared__ int lds_hist[4][NW][HPAD];   // ~16.9 KB, reused as tie-list later
    __shared__ int lds_seldig;
    __shared__ int lds_R, lds_E, lds_cnt;

    const int t = threadIdx.x;
    const int row = blockIdx.x;
    const int lane = t & 63;
    const int w = t >> 6;

    const float4* x4 = (const float4*)(x + (size_t)row * NCOL);
    const float4* b4 = (const float4*)g_boost;

    unsigned kr[VPT][4];

    // zero all 4 pass-histograms up front (one sync covers everything)
    {
        int* lz = &lds_hist[0][0][0];
        for (int i = t; i < 4 * NW * HPAD; i += TPB) lz[i] = 0;
        if (t == 0) { lds_R = KSEL; lds_E = 0; }
    }

    // load x + boost, compute sortable keys (keys live in registers only)
#pragma unroll
    for (int j = 0; j < VPT; ++j) {
        const int v = t + TPB * j;
        float4 xx = x4[v];
        float4 bb = b4[v];
        kr[j][0] = f2k(xx.x * bb.x);
        kr[j][1] = f2k(xx.y * bb.y);
        kr[j][2] = f2k(xx.z * bb.z);
        kr[j][3] = f2k(xx.w * bb.w);
    }
    __syncthreads();

    unsigned prefix = 0;

    // 4-pass radix select (MSB->LSB): exact key of K-th largest
#pragma unroll
    for (int p = 0; p < 4; ++p) {
        const int sh = 24 - 8 * p;
        // histogram (per-wave privatized copies)
#pragma unroll
        for (int j = 0; j < VPT; ++j) {
#pragma unroll
            for (int c = 0; c < 4; ++c) {
                unsigned key = kr[j][c];
                bool in = (p == 0) || (((key ^ prefix) >> (sh + 8)) == 0u);
                if (in) atomicAdd(&lds_hist[p][w][(key >> sh) & 255u], 1);
            }
        }
        __syncthreads();
        // wave 0: sum wave-copies, suffix-scan 256 bins (4 bins/lane), select
        if (w == 0) {
            int4 h0 = *(const int4*)&lds_hist[p][0][lane * 4];
            int4 h1 = *(const int4*)&lds_hist[p][1][lane * 4];
            int4 h2 = *(const int4*)&lds_hist[p][2][lane * 4];
            int4 h3 = *(const int4*)&lds_hist[p][3][lane * 4];
            const int b0 = h0.x + h1.x + h2.x + h3.x;
            const int b1 = h0.y + h1.y + h2.y + h3.y;
            const int b2 = h0.z + h1.z + h2.z + h3.z;
            const int b3 = h0.w + h1.w + h2.w + h3.w;
            int s = b0 + b1 + b2 + b3;
            // inclusive suffix scan across 64 lanes
#pragma unroll
            for (int off = 1; off < 64; off <<= 1) {
                int o = __shfl_down(s, off);
                if (lane + off < 64) s += o;
            }
            const int R0 = lds_R;
            const int Sx0 = s - b0;          // # keys in bins > 4*lane+0
            const int Sx1 = Sx0 - b1;
            const int Sx2 = Sx1 - b2;
            const int Sx3 = Sx2 - b3;
            int selb = -1, selR = 0, selE = 0;
            if (Sx0 < R0 && s >= R0)          { selb = 4 * lane + 0; selR = R0 - Sx0; selE = b0; }
            else if (Sx1 < R0 && Sx0 >= R0)   { selb = 4 * lane + 1; selR = R0 - Sx1; selE = b1; }
            else if (Sx2 < R0 && Sx1 >= R0)   { selb = 4 * lane + 2; selR = R0 - Sx2; selE = b2; }
            else if (Sx3 < R0 && Sx2 >= R0)   { selb = 4 * lane + 3; selR = R0 - Sx3; selE = b3; }
            if (selb >= 0) { lds_seldig = selb; lds_R = selR; lds_E = selE; }
        }
        __syncthreads();
        prefix |= ((unsigned)lds_seldig) << sh;
    }

    const unsigned thresh = prefix;   // exact key of the K-th largest
    const int Rf = lds_R;             // how many equal-to-thresh to keep
    const int E = lds_E;              // total equal-to-thresh
    unsigned dropm = 0;               // per-element demote bits (ties only)

    if (E > Rf) {                     // tie-break: keep lowest indices (lax.top_k)
        unsigned short* list = (unsigned short*)&lds_hist[0][0][0];  // cap 8448 >= NCOL
        if (t == 0) lds_cnt = 0;
        __syncthreads();
#pragma unroll
        for (int j = 0; j < VPT; ++j) {
#pragma unroll
            for (int c = 0; c < 4; ++c) {
                if (kr[j][c] == thresh) {
                    int slot = atomicAdd(&lds_cnt, 1);
                    list[slot] = (unsigned short)(4 * (t + TPB * j) + c);
                }
            }
        }
        __syncthreads();
        const int n = lds_cnt;
#pragma unroll
        for (int j = 0; j < VPT; ++j) {
#pragma unroll
            for (int c = 0; c < 4; ++c) {
                if (kr[j][c] == thresh) {
                    const int col = 4 * (t + TPB * j) + c;
                    int rank = 0;
                    for (int i = 0; i < n; ++i) rank += (list[i] < col) ? 1 : 0;
                    if (rank >= Rf) dropm |= (1u << (j * 4 + c));
                }
            }
        }
    }

    // write: transmit ORIGINAL x at winners, 0 elsewhere (x reloaded, L2-hot)
    float4* o4 = (float4*)(out + (size_t)row * NCOL);
#pragma unroll
    for (int j = 0; j < VPT; ++j) {
        const int v = t + TPB * j;
        float4 xx = x4[v];
        float4 r;
        r.x = (kr[j][0] >= thresh && !((dropm >> (j * 4 + 0)) & 1u)) ? xx.x : 0.0f;
        r.y = (kr[j][1] >= thresh && !((dropm >> (j * 4 + 1)) & 1u)) ? xx.y : 0.0f;
        r.z = (kr[j][2] >= thresh && !((dropm >> (j * 4 + 2)) & 1u)) ? xx.z : 0.0f;
        r.w = (kr[j][3] >= thresh && !((dropm >> (j * 4 + 3)) & 1u)) ? xx.w : 0.0f;
        o4[v] = r;
    }
}

extern "C" void kernel_launch(void* const* d_in, const int* in_sizes, int n_in,
                              void* d_out, int out_size, void* d_ws, size_t ws_size,
                              hipStream_t stream) {
    const float* x = (const float*)d_in[0];        // [4096, 8192] f32
    const float* duty = (const float*)d_in[1];     // [8192] f32
    float* out = (float*)d_out;                    // [4096, 8192] f32
    (void)in_sizes; (void)n_in; (void)out_size; (void)d_ws; (void)ws_size;

    boost_kernel<<<(NCOL + TPB - 1) / TPB, TPB, 0, stream>>>(duty);
    kwinners_kernel<<<NROW, TPB, 0, stream>>>(x, out);
}

// Round 3
// 64.989 us; speedup vs baseline: 2.2055x; 2.2055x over previous
//
#include <hip/hip_runtime.h>
#include <math.h>

#define NCOL 8192
#define NROW 4096
#define KSEL 819
#define TPB  512
#define VPT  4            // float4 per thread (16 elements/thread)
#define NWAVE 8
#define NSUB 4            // pass-0 sub-histograms per wave (one per 16 lanes)
#define H0STRIDE 260      // 256 bins + 4 pad ints -> copies shift banks by 4

// Per-column boost factors, recomputed every launch (deterministic).
__device__ __align__(16) float g_boost[NCOL];

__global__ void boost_kernel(const float* __restrict__ duty) {
    int i = blockIdx.x * blockDim.x + threadIdx.x;
    if (i < NCOL) {
        // target_density = 819/8192 exactly; boost_strength = 1
        float diff = (0.0999755859375f - duty[i]);
        g_boost[i] = (float)exp((double)diff);   // correctly-rounded f32 exp (matches np)
    }
}

__device__ __forceinline__ unsigned f2k(float f) {
    // monotone float -> uint map (total order)
    unsigned u = __float_as_uint(f);
    return u ^ (0x80000000u | (unsigned)((int)u >> 31));
}

__global__ __launch_bounds__(TPB) void kwinners_kernel(const float* __restrict__ x,
                                                       float* __restrict__ out) {
    __shared__ __align__(16) int h0[NWAVE * NSUB * H0STRIDE]; // pass-0 privatized (~33.3 KB)
    __shared__ __align__(16) int hp[3][256];                  // passes 1-3 shared (3 KB)
    __shared__ __align__(16) int tot[256];                    // summed pass-0 bins
    __shared__ int lds_sel, lds_R, lds_E, lds_cnt;

    const int t = threadIdx.x;
    const int row = blockIdx.x;
    const int lane = t & 63;
    const int w = t >> 6;

    const float4* x4 = (const float4*)(x + (size_t)row * NCOL);
    const float4* b4 = (const float4*)g_boost;

    float4 xv[VPT];
    unsigned kr[VPT][4];

    // zero histograms (single sync covers everything)
    for (int i = t; i < NWAVE * NSUB * H0STRIDE; i += TPB) h0[i] = 0;
    for (int i = t; i < 3 * 256; i += TPB) ((int*)hp)[i] = 0;
    if (t == 0) { lds_R = KSEL; lds_E = 0; }

    // load x + boost, compute sortable keys; x and keys stay in registers
#pragma unroll
    for (int j = 0; j < VPT; ++j) {
        const int v = t + TPB * j;
        float4 xx = x4[v];
        float4 bb = b4[v];
        xv[j] = xx;
        kr[j][0] = f2k(xx.x * bb.x);
        kr[j][1] = f2k(xx.y * bb.y);
        kr[j][2] = f2k(xx.z * bb.z);
        kr[j][3] = f2k(xx.w * bb.w);
    }
    __syncthreads();

    // ---- pass 0 histogram: per-16-lane-group private copies ----
    int* myh = &h0[(w * NSUB + (lane >> 4)) * H0STRIDE];
#pragma unroll
    for (int j = 0; j < VPT; ++j) {
#pragma unroll
        for (int c = 0; c < 4; ++c) atomicAdd(&myh[kr[j][c] >> 24], 1);
    }
    __syncthreads();

    // sum the 32 copies per bin
    if (t < 256) {
        int s = 0;
#pragma unroll
        for (int i = 0; i < NWAVE * NSUB; ++i) s += h0[i * H0STRIDE + t];
        tot[t] = s;
    }
    __syncthreads();

    // ---- 4-pass radix select (MSB->LSB): exact key of K-th largest ----
    unsigned prefix = 0;
#pragma unroll
    for (int p = 0; p < 4; ++p) {
        const int sh = 24 - 8 * p;
        // wave 0: suffix-scan 256 bins (4 bins/lane), pick the bin holding rank R
        if (w == 0) {
            const int* src = (p == 0) ? tot : hp[p - 1];
            int4 hh = *(const int4*)&src[lane * 4];
            const int b0 = hh.x, b1 = hh.y, b2 = hh.z, b3 = hh.w;
            int s = b0 + b1 + b2 + b3;
#pragma unroll
            for (int off = 1; off < 64; off <<= 1) {
                int o = __shfl_down(s, off);
                if (lane + off < 64) s += o;
            }
            const int R0 = lds_R;
            const int Sx0 = s - b0;          // # keys in bins > 4*lane+0
            const int Sx1 = Sx0 - b1;
            const int Sx2 = Sx1 - b2;
            const int Sx3 = Sx2 - b3;
            int selb = -1, selR = 0, selE = 0;
            if (Sx0 < R0 && s >= R0)          { selb = 4 * lane + 0; selR = R0 - Sx0; selE = b0; }
            else if (Sx1 < R0 && Sx0 >= R0)   { selb = 4 * lane + 1; selR = R0 - Sx1; selE = b1; }
            else if (Sx2 < R0 && Sx1 >= R0)   { selb = 4 * lane + 2; selR = R0 - Sx2; selE = b2; }
            else if (Sx3 < R0 && Sx2 >= R0)   { selb = 4 * lane + 3; selR = R0 - Sx3; selE = b3; }
            if (selb >= 0) { lds_sel = selb; lds_R = selR; lds_E = selE; }
        }
        __syncthreads();
        prefix |= ((unsigned)lds_sel) << sh;
        // histogram next digit over elements matching the prefix (rare -> shared hist ok)
        if (p < 3) {
            const int shn = sh - 8;
#pragma unroll
            for (int j = 0; j < VPT; ++j) {
#pragma unroll
                for (int c = 0; c < 4; ++c) {
                    unsigned key = kr[j][c];
                    if (((key ^ prefix) >> sh) == 0u)
                        atomicAdd(&hp[p][(key >> shn) & 255u], 1);
                }
            }
            __syncthreads();
        }
    }

    const unsigned thresh = prefix;   // exact key of the K-th largest
    const int Rf = lds_R;             // how many equal-to-thresh to keep
    const int E = lds_E;              // total equal-to-thresh
    unsigned dropm = 0;               // per-element demote bits (ties only)

    if (E > Rf) {                     // tie-break: keep lowest indices (lax.top_k)
        unsigned short* list = (unsigned short*)h0;   // reuse, cap 16.6K >= NCOL
        if (t == 0) lds_cnt = 0;
        __syncthreads();
#pragma unroll
        for (int j = 0; j < VPT; ++j) {
#pragma unroll
            for (int c = 0; c < 4; ++c) {
                if (kr[j][c] == thresh) {
                    int slot = atomicAdd(&lds_cnt, 1);
                    list[slot] = (unsigned short)(4 * (t + TPB * j) + c);
                }
            }
        }
        __syncthreads();
        const int n = lds_cnt;
#pragma unroll
        for (int j = 0; j < VPT; ++j) {
#pragma unroll
            for (int c = 0; c < 4; ++c) {
                if (kr[j][c] == thresh) {
                    const int col = 4 * (t + TPB * j) + c;
                    int rank = 0;
                    for (int i = 0; i < n; ++i) rank += (list[i] < col) ? 1 : 0;
                    if (rank >= Rf) dropm |= (1u << (4 * j + c));
                }
            }
        }
    }

    // write: transmit ORIGINAL x (from registers) at winners, 0 elsewhere
    float4* o4 = (float4*)(out + (size_t)row * NCOL);
#pragma unroll
    for (int j = 0; j < VPT; ++j) {
        const int v = t + TPB * j;
        float4 r;
        r.x = (kr[j][0] >= thresh && !((dropm >> (4 * j + 0)) & 1u)) ? xv[j].x : 0.0f;
        r.y = (kr[j][1] >= thresh && !((dropm >> (4 * j + 1)) & 1u)) ? xv[j].y : 0.0f;
        r.z = (kr[j][2] >= thresh && !((dropm >> (4 * j + 2)) & 1u)) ? xv[j].z : 0.0f;
        r.w = (kr[j][3] >= thresh && !((dropm >> (4 * j + 3)) & 1u)) ? xv[j].w : 0.0f;
        o4[v] = r;
    }
}

extern "C" void kernel_launch(void* const* d_in, const int* in_sizes, int n_in,
                              void* d_out, int out_size, void* d_ws, size_t ws_size,
                              hipStream_t stream) {
    const float* x = (const float*)d_in[0];        // [4096, 8192] f32
    const float* duty = (const float*)d_in[1];     // [8192] f32
    float* out = (float*)d_out;                    // [4096, 8192] f32
    (void)in_sizes; (void)n_in; (void)out_size; (void)d_ws; (void)ws_size;

    boost_kernel<<<(NCOL + TPB - 1) / TPB, TPB, 0, stream>>>(duty);
    kwinners_kernel<<<NROW, TPB, 0, stream>>>(x, out);
}